// Round 2
// baseline (762.889 us; speedup 1.0000x reference)
//
#include <hip/hip_runtime.h>

#define S 2048
#define Dh 128
#define NB 16
#define OUT_ELEMS ((size_t)NB * S * Dh)   // 4194304 floats (16 MB region before attn)
#define NEG_BIG -1.0e9f
#define SCALE 0.08838834764831845f        // 1/sqrt(128)

typedef __attribute__((ext_vector_type(8))) short bf16x8;
typedef __attribute__((ext_vector_type(4))) float f32x4;
typedef __attribute__((ext_vector_type(4))) short s16x4;

__device__ __forceinline__ short f2bf(float x) {
    unsigned u = __float_as_uint(x);
    u += 0x7fffu + ((u >> 16) & 1u);      // RNE truncate to bf16 (no NaN inputs here)
    return (short)(u >> 16);
}

__device__ __forceinline__ s16x4 pack4(float4 v) {
    s16x4 r;
    r.x = f2bf(v.x); r.y = f2bf(v.y); r.z = f2bf(v.z); r.w = f2bf(v.w);
    return r;
}

// ---------------------------------------------------------------------------
// Mask dtype detection: int32-encoded bool has bytes 1..3 of each word == 0;
// u8-encoded random 0/1 mask has nonzero there with overwhelming probability.
// flag = 1 -> uint8 mask, flag = 0 -> int32 mask.
// ---------------------------------------------------------------------------
__global__ void detect_mask(const unsigned char* __restrict__ m, int* __restrict__ flag) {
    __shared__ int any;
    if (threadIdx.x == 0) any = 0;
    __syncthreads();
    int t = threadIdx.x;
    unsigned char v = (unsigned char)(m[t * 4 + 1] | m[t * 4 + 2] | m[t * 4 + 3]);
    if (v) atomicOr(&any, 1);
    __syncthreads();
    if (t == 0) *flag = any;
}

// ---------------------------------------------------------------------------
// V [b][k][n] fp32  ->  Vt [b][n][k] bf16 (k contiguous for MFMA B-fragments)
// grid: (32 k-blocks of 64, NB)
// ---------------------------------------------------------------------------
__global__ __launch_bounds__(256) void transpose_v(const float* __restrict__ V,
                                                   short* __restrict__ Vt) {
    const int kb = blockIdx.x, b = blockIdx.y;
    const float* Vb = V + ((size_t)b * S + kb * 64) * Dh;
    short* VtB = Vt + (size_t)b * Dh * S;
    __shared__ float Ls[64][132];
    const int t = threadIdx.x;
#pragma unroll
    for (int i = 0; i < 8; i++) {
        int idx = t + i * 256;
        int r = idx >> 5, c = (idx & 31) << 2;
        *(float4*)&Ls[r][c] = *(const float4*)(Vb + r * Dh + c);
    }
    __syncthreads();
#pragma unroll
    for (int i = 0; i < 8; i++) {
        int idx = t + i * 256;
        int n = idx >> 4, kc = (idx & 15) << 2;
        s16x4 o;
        o.x = f2bf(Ls[kc + 0][n]);
        o.y = f2bf(Ls[kc + 1][n]);
        o.z = f2bf(Ls[kc + 2][n]);
        o.w = f2bf(Ls[kc + 3][n]);
        *(s16x4*)(VtB + (size_t)n * S + kb * 64 + kc) = o;
    }
}

// ---------------------------------------------------------------------------
// Scores = mask( (Q . K^T) * SCALE )  written into attn region (masked -> -1e9).
// When fuse=1 also computes per-tile row (max, sum-exp) partials:
//   part[(b*16+kt)*S + row] = (m, l)  for this kt column-block of 128.
// gemm_bt pattern, mfma_f32_16x16x32_bf16, 128x128 tile, BK=64 (2 iters).
// grid: (16 kt, 16 qt, NB), block 256 (4 waves as 2x2 quadrants of 64x64).
// ---------------------------------------------------------------------------
__global__ __launch_bounds__(256, 2) void qk_kernel(const float* __restrict__ Q,
                                                    const float* __restrict__ Km,
                                                    float* __restrict__ Sc,
                                                    const void* __restrict__ maskp,
                                                    const int* __restrict__ flagp,
                                                    float2* __restrict__ part,
                                                    const int fuse) {
    const int kt = blockIdx.x, qt = blockIdx.y, b = blockIdx.z;
    const float* Qb = Q + ((size_t)b * S + qt * 128) * Dh;
    const float* Kb = Km + ((size_t)b * S + kt * 128) * Dh;
    __shared__ short As[128][72];
    __shared__ short Bs[128][72];
    __shared__ __align__(16) unsigned char Ms[128][144];   // 144 = 16*9: int4-aligned rows, bank-spread
    const int t = threadIdx.x;
    const int w = t >> 6, lane = t & 63, fr = lane & 15, quad = lane >> 4;
    const int mw = (w >> 1) * 64, nw = (w & 1) * 64;
    f32x4 acc[4][4] = {};

    // Stage the 128x128 mask tile as bytes (consumed only in the epilogue; the
    // K-loop barriers order it against the reads).
    if (fuse) {
        const int flag = *flagp;
        if (flag) {   // uint8 mask
            const unsigned char* Mb = (const unsigned char*)maskp + ((size_t)b * S + qt * 128) * S + (size_t)kt * 128;
#pragma unroll
            for (int i = 0; i < 4; i++) {
                int idx = t + i * 256;
                int r = idx >> 3, c = (idx & 7) * 16;
                *(int4*)&Ms[r][c] = *(const int4*)(Mb + (size_t)r * S + c);
            }
        } else {      // int32 mask
            const int* Mb = (const int*)maskp + ((size_t)b * S + qt * 128) * S + (size_t)kt * 128;
#pragma unroll
            for (int i = 0; i < 16; i++) {
                int idx = t + i * 256;
                int r = idx >> 5, c = (idx & 31) * 4;
                int4 m = *(const int4*)(Mb + (size_t)r * S + c);
                uchar4 o;
                o.x = (unsigned char)(m.x != 0);
                o.y = (unsigned char)(m.y != 0);
                o.z = (unsigned char)(m.z != 0);
                o.w = (unsigned char)(m.w != 0);
                *(uchar4*)&Ms[r][c] = o;
            }
        }
    }

    for (int k0 = 0; k0 < Dh; k0 += 64) {
        __syncthreads();
#pragma unroll
        for (int i = 0; i < 8; i++) {
            int idx = t + i * 256;
            int r = idx >> 4, c = (idx & 15) << 2;   // 16 float4 per 64-col row
            float4 qv = *(const float4*)(Qb + r * Dh + k0 + c);
            float4 kv = *(const float4*)(Kb + r * Dh + k0 + c);
            *(s16x4*)&As[r][c] = pack4(qv);
            *(s16x4*)&Bs[r][c] = pack4(kv);
        }
        __syncthreads();
#pragma unroll
        for (int kc = 0; kc < 2; kc++) {
            const int ko = kc * 32 + quad * 8;
            bf16x8 af[4], bf[4];
#pragma unroll
            for (int mi = 0; mi < 4; mi++) af[mi] = *(const bf16x8*)&As[mw + mi * 16 + fr][ko];
#pragma unroll
            for (int ni = 0; ni < 4; ni++) bf[ni] = *(const bf16x8*)&Bs[nw + ni * 16 + fr][ko];
#pragma unroll
            for (int mi = 0; mi < 4; mi++)
#pragma unroll
                for (int ni = 0; ni < 4; ni++)
                    acc[mi][ni] = __builtin_amdgcn_mfma_f32_16x16x32_bf16(af[mi], bf[ni], acc[mi][ni], 0, 0, 0);
        }
    }

    // As is dead after the last fragment loads; reuse it for per-row partials.
    __syncthreads();
    float2* pm = (float2*)&As[0][0];          // [128][2] float2 = 2 KB
    float* ScB = Sc + (size_t)b * S * S;
#pragma unroll
    for (int mi = 0; mi < 4; mi++)
#pragma unroll
        for (int r = 0; r < 4; r++) {
            const int lrow = mw + mi * 16 + quad * 4 + r;     // C: row = quad*4+reg
            const size_t grow = (size_t)(qt * 128 + lrow);
            float s[4];
#pragma unroll
            for (int ni = 0; ni < 4; ni++) {
                const int lcol = nw + ni * 16 + fr;           // C: col = lane&15
                float v = acc[mi][ni][r] * SCALE;
                if (fuse && Ms[lrow][lcol]) v = NEG_BIG;
                s[ni] = v;
                ScB[grow * S + kt * 128 + lcol] = v;
            }
            if (fuse) {
                float mx = fmaxf(fmaxf(s[0], s[1]), fmaxf(s[2], s[3]));
#pragma unroll
                for (int o = 8; o > 0; o >>= 1) mx = fmaxf(mx, __shfl_xor(mx, o, 64));
                float l = __expf(s[0] - mx) + __expf(s[1] - mx) +
                          __expf(s[2] - mx) + __expf(s[3] - mx);
#pragma unroll
                for (int o = 8; o > 0; o >>= 1) l += __shfl_xor(l, o, 64);
                if (fr == 0) pm[lrow * 2 + (w & 1)] = make_float2(mx, l);
            }
        }

    if (fuse) {
        __syncthreads();
        if (t < 128) {
            float2 a = pm[t * 2 + 0], c = pm[t * 2 + 1];
            float M = fmaxf(a.x, c.x);
            float L = a.y * __expf(a.x - M) + c.y * __expf(c.x - M);
            part[((size_t)(b * 16 + kt)) * S + qt * 128 + t] = make_float2(M, L);
        }
    }
}

// ---------------------------------------------------------------------------
// Fold 16 per-kt partials into per-row (M, 1/L). grid: NB*S/256 blocks.
// ---------------------------------------------------------------------------
__global__ __launch_bounds__(256) void reduce_stats(const float2* __restrict__ part,
                                                    float2* __restrict__ stats) {
    const int rid = blockIdx.x * 256 + threadIdx.x;   // [0, NB*S)
    const int b = rid >> 11, row = rid & (S - 1);
    float2 p[16];
    float M = -3.4e38f;
#pragma unroll
    for (int kt = 0; kt < 16; kt++) {
        p[kt] = part[((size_t)(b * 16 + kt)) * S + row];
        M = fmaxf(M, p[kt].x);
    }
    float L = 0.f;
#pragma unroll
    for (int kt = 0; kt < 16; kt++) L += p[kt].y * __expf(p[kt].x - M);
    stats[rid] = make_float2(M, 1.0f / L);
}

// ---------------------------------------------------------------------------
// Row-wise mask + softmax, in place on the attn region. (FALLBACK path only.)
// ---------------------------------------------------------------------------
__global__ __launch_bounds__(256) void softmax_kernel(float* __restrict__ Sc,
                                                      const void* __restrict__ maskp,
                                                      const int* __restrict__ flagp) {
    const int b = blockIdx.y;
    const int w = threadIdx.x >> 6, lane = threadIdx.x & 63;
    const int row = blockIdx.x * 4 + w;
    float* R = Sc + ((size_t)b * S + row) * S;
    float4* R4 = (float4*)R;
    const int flag = flagp ? *flagp : 0;

    float sv[32];
    if (flag) {
        const uchar4* M4 = (const uchar4*)((const unsigned char*)maskp + ((size_t)b * S + row) * S);
#pragma unroll
        for (int j = 0; j < 8; j++) {
            float4 v = R4[lane + 64 * j];
            uchar4 m = M4[lane + 64 * j];
            sv[4 * j + 0] = m.x ? NEG_BIG : v.x;
            sv[4 * j + 1] = m.y ? NEG_BIG : v.y;
            sv[4 * j + 2] = m.z ? NEG_BIG : v.z;
            sv[4 * j + 3] = m.w ? NEG_BIG : v.w;
        }
    } else {
        const int4* M4 = (const int4*)((const int*)maskp + ((size_t)b * S + row) * S);
#pragma unroll
        for (int j = 0; j < 8; j++) {
            float4 v = R4[lane + 64 * j];
            int4 m = M4[lane + 64 * j];
            sv[4 * j + 0] = m.x ? NEG_BIG : v.x;
            sv[4 * j + 1] = m.y ? NEG_BIG : v.y;
            sv[4 * j + 2] = m.z ? NEG_BIG : v.z;
            sv[4 * j + 3] = m.w ? NEG_BIG : v.w;
        }
    }

    float mx = sv[0];
#pragma unroll
    for (int i = 1; i < 32; i++) mx = fmaxf(mx, sv[i]);
    for (int o = 32; o > 0; o >>= 1) mx = fmaxf(mx, __shfl_xor(mx, o, 64));

    float sum = 0.f;
#pragma unroll
    for (int i = 0; i < 32; i++) {
        sv[i] = __expf(sv[i] - mx);
        sum += sv[i];
    }
    for (int o = 32; o > 0; o >>= 1) sum += __shfl_xor(sum, o, 64);
    const float inv = 1.0f / sum;

#pragma unroll
    for (int j = 0; j < 8; j++) {
        float4 p;
        p.x = sv[4 * j + 0] * inv;
        p.y = sv[4 * j + 1] * inv;
        p.z = sv[4 * j + 2] * inv;
        p.w = sv[4 * j + 3] * inv;
        R4[lane + 64 * j] = p;
    }
}

// ---------------------------------------------------------------------------
// out = attn . V.  64-row M-tiles (grid 32 x NB = 512 blocks, 2/CU).
// fuse=1: Sc holds masked raw scores; staging applies p=exp(s-M)*invL, writes
// the final attn value in place, and feeds p to the MFMA A-operand.
// fuse=0: Sc already holds probabilities (fallback path), no write.
// ---------------------------------------------------------------------------
__global__ __launch_bounds__(256, 2) void pv_kernel(float* __restrict__ Sc,
                                                    const float* __restrict__ V,
                                                    const short* __restrict__ Vt,
                                                    const int useVt,
                                                    float* __restrict__ Out,
                                                    const float2* __restrict__ stats,
                                                    const int fuse) {
    const int mt = blockIdx.x, b = blockIdx.y;
    float* ScB = Sc + (size_t)b * S * S + (size_t)mt * 64 * S;
    const float* Vb = V + (size_t)b * S * Dh;
    const short* VtB = Vt + (size_t)b * Dh * S;
    float* OutB = Out + ((size_t)b * S + mt * 64) * Dh;
    __shared__ short As[64][72];
    __shared__ float2 sstat[64];
    const int t = threadIdx.x, w = t >> 6, lane = t & 63, fr = lane & 15, quad = lane >> 4;
    const int mw = (w >> 1) * 32, nw = (w & 1) * 64;
    f32x4 acc[2][4] = {};

    if (fuse && t < 64) sstat[t] = stats[(size_t)b * S + mt * 64 + t];

    for (int k0 = 0; k0 < S; k0 += 64) {
        __syncthreads();
#pragma unroll
        for (int i = 0; i < 4; i++) {
            int idx = t + i * 256;
            int r = idx >> 4, c = (idx & 15) << 2;
            float4 v = *(const float4*)(ScB + (size_t)r * S + k0 + c);
            if (fuse) {
                float2 st = sstat[r];
                v.x = __expf(v.x - st.x) * st.y;
                v.y = __expf(v.y - st.x) * st.y;
                v.z = __expf(v.z - st.x) * st.y;
                v.w = __expf(v.w - st.x) * st.y;
                *(float4*)(ScB + (size_t)r * S + k0 + c) = v;   // final attn value
            }
            *(s16x4*)&As[r][c] = pack4(v);
        }
        __syncthreads();
#pragma unroll
        for (int kc = 0; kc < 2; kc++) {
            const int ko = kc * 32 + quad * 8;
            bf16x8 af[2], bf[4];
#pragma unroll
            for (int mi = 0; mi < 2; mi++) af[mi] = *(const bf16x8*)&As[mw + mi * 16 + fr][ko];
            if (useVt) {
#pragma unroll
                for (int ni = 0; ni < 4; ni++)
                    bf[ni] = *(const bf16x8*)(VtB + (size_t)(nw + ni * 16 + fr) * S + k0 + ko);
            } else {
#pragma unroll
                for (int ni = 0; ni < 4; ni++) {
                    int n = nw + ni * 16 + fr;
#pragma unroll
                    for (int j = 0; j < 8; j++) bf[ni][j] = f2bf(Vb[(size_t)(k0 + ko + j) * Dh + n]);
                }
            }
#pragma unroll
            for (int mi = 0; mi < 2; mi++)
#pragma unroll
                for (int ni = 0; ni < 4; ni++)
                    acc[mi][ni] = __builtin_amdgcn_mfma_f32_16x16x32_bf16(af[mi], bf[ni], acc[mi][ni], 0, 0, 0);
        }
    }

#pragma unroll
    for (int mi = 0; mi < 2; mi++)
#pragma unroll
        for (int ni = 0; ni < 4; ni++)
#pragma unroll
            for (int r = 0; r < 4; r++) {
                int row = mw + mi * 16 + quad * 4 + r;
                int col = nw + ni * 16 + fr;
                OutB[(size_t)row * Dh + col] = acc[mi][ni][r];
            }
}

extern "C" void kernel_launch(void* const* d_in, const int* in_sizes, int n_in,
                              void* d_out, int out_size, void* d_ws, size_t ws_size,
                              hipStream_t stream) {
    const float* Q = (const float*)d_in[0];
    const float* Km = (const float*)d_in[1];
    const float* V = (const float*)d_in[2];
    const void* M = d_in[3];
    float* out = (float*)d_out;
    float* attn = out + OUT_ELEMS;

    const size_t VT_BYTES = (size_t)NB * Dh * S * sizeof(short);    // 8 MB
    const size_t STATS_BYTES = (size_t)NB * S * sizeof(float2);     // 256 KB

    int useVt = 0, fuse = 0;
    short* Vt = nullptr;
    float2* stats = nullptr;
    int* flag = nullptr;

    if (ws_size >= VT_BYTES + STATS_BYTES + 64) {
        useVt = 1; fuse = 1;
        Vt = (short*)d_ws;
        stats = (float2*)((char*)d_ws + VT_BYTES);
        flag = (int*)((char*)d_ws + VT_BYTES + STATS_BYTES);
    } else if (ws_size >= VT_BYTES + 64) {
        useVt = 1;
        Vt = (short*)d_ws;
        flag = (int*)((char*)d_ws + VT_BYTES);
    } else if (ws_size >= 64) {
        flag = (int*)d_ws;
    }

    // Per-(row, kt) softmax partials live in the `out` region of d_out: it is
    // 16 MB, partials are 4 MB, and pv (which writes `out`) runs strictly
    // after reduce_stats has consumed them (stream order).
    float2* part = (float2*)d_out;

    if (flag) detect_mask<<<1, 256, 0, stream>>>((const unsigned char*)M, flag);
    if (useVt) transpose_v<<<dim3(32, NB), 256, 0, stream>>>(V, Vt);

    qk_kernel<<<dim3(16, 16, NB), 256, 0, stream>>>(Q, Km, attn, M, flag, part, fuse);

    if (fuse) {
        reduce_stats<<<dim3((NB * S) / 256), 256, 0, stream>>>(part, stats);
        pv_kernel<<<dim3(32, NB), 256, 0, stream>>>(attn, V, Vt, useVt, out, stats, 1);
    } else {
        softmax_kernel<<<dim3(512, NB), 256, 0, stream>>>(attn, M, flag);
        pv_kernel<<<dim3(32, NB), 256, 0, stream>>>(attn, V, Vt, useVt, out, nullptr, 0);
    }
}

// Round 3
// 691.483 us; speedup vs baseline: 1.1033x; 1.1033x over previous
//
#include <hip/hip_runtime.h>

#define S 2048
#define Dh 128
#define NB 16
#define OUT_ELEMS ((size_t)NB * S * Dh)   // 4194304 floats (16 MB region before attn)
#define NEG_BIG -1.0e9f
#define SCALE 0.08838834764831845f        // 1/sqrt(128)

typedef __attribute__((ext_vector_type(8))) short bf16x8;
typedef __attribute__((ext_vector_type(4))) float f32x4;
typedef __attribute__((ext_vector_type(4))) short s16x4;

__device__ __forceinline__ short f2bf(float x) {
    unsigned u = __float_as_uint(x);
    u += 0x7fffu + ((u >> 16) & 1u);      // RNE truncate to bf16 (no NaN inputs here)
    return (short)(u >> 16);
}

__device__ __forceinline__ s16x4 pack4(float4 v) {
    s16x4 r;
    r.x = f2bf(v.x); r.y = f2bf(v.y); r.z = f2bf(v.z); r.w = f2bf(v.w);
    return r;
}

// ---------------------------------------------------------------------------
// Mask dtype detection: int32-encoded bool has bytes 1..3 of each word == 0.
// flag = 1 -> uint8 mask, flag = 0 -> int32 mask.
// ---------------------------------------------------------------------------
__global__ void detect_mask(const unsigned char* __restrict__ m, int* __restrict__ flag) {
    __shared__ int any;
    if (threadIdx.x == 0) any = 0;
    __syncthreads();
    int t = threadIdx.x;
    unsigned char v = (unsigned char)(m[t * 4 + 1] | m[t * 4 + 2] | m[t * 4 + 3]);
    if (v) atomicOr(&any, 1);
    __syncthreads();
    if (t == 0) *flag = any;
}

// ---------------------------------------------------------------------------
// V [b][k][n] fp32  ->  Vt [b][n][k] bf16 (k contiguous for MFMA B-fragments)
// ---------------------------------------------------------------------------
__global__ __launch_bounds__(256) void transpose_v(const float* __restrict__ V,
                                                   short* __restrict__ Vt) {
    const int kb = blockIdx.x, b = blockIdx.y;
    const float* Vb = V + ((size_t)b * S + kb * 64) * Dh;
    short* VtB = Vt + (size_t)b * Dh * S;
    __shared__ float Ls[64][132];
    const int t = threadIdx.x;
#pragma unroll
    for (int i = 0; i < 8; i++) {
        int idx = t + i * 256;
        int r = idx >> 5, c = (idx & 31) << 2;
        *(float4*)&Ls[r][c] = *(const float4*)(Vb + r * Dh + c);
    }
    __syncthreads();
#pragma unroll
    for (int i = 0; i < 8; i++) {
        int idx = t + i * 256;
        int n = idx >> 4, kc = (idx & 15) << 2;
        s16x4 o;
        o.x = f2bf(Ls[kc + 0][n]);
        o.y = f2bf(Ls[kc + 1][n]);
        o.z = f2bf(Ls[kc + 2][n]);
        o.w = f2bf(Ls[kc + 3][n]);
        *(s16x4*)(VtB + (size_t)n * S + kb * 64 + kc) = o;
    }
}

// ---------------------------------------------------------------------------
// fp32 -> bf16 row-major copy (Q and K pre-conversion).
// ---------------------------------------------------------------------------
__global__ __launch_bounds__(256) void cvt_bf16(const float* __restrict__ in,
                                                short* __restrict__ out) {
    const size_t n4 = (size_t)NB * S * Dh / 4;
    for (size_t i = (size_t)blockIdx.x * 256 + threadIdx.x; i < n4; i += (size_t)gridDim.x * 256) {
        float4 v = ((const float4*)in)[i];
        ((s16x4*)out)[i] = pack4(v);
    }
}

// ---------------------------------------------------------------------------
// PASS 1: per-(row, kt-tile) masked-softmax partials (m, l). NO score write.
// Reads pre-converted bf16 Q/K. grid (16 kt, 16 qt, NB), 256 thr.
// MFMA k-accumulate order identical to fused_pv so scores match bitwise.
// ---------------------------------------------------------------------------
__global__ __launch_bounds__(256, 2) void qk_stats(const short* __restrict__ Qbf,
                                                   const short* __restrict__ Kbf,
                                                   const void* __restrict__ maskp,
                                                   const int* __restrict__ flagp,
                                                   float2* __restrict__ part) {
    const int kt = blockIdx.x, qt = blockIdx.y, b = blockIdx.z;
    const short* Qb = Qbf + ((size_t)b * S + qt * 128) * Dh;
    const short* Kb = Kbf + ((size_t)b * S + kt * 128) * Dh;
    __shared__ short As[128][72];
    __shared__ short Bs[128][72];
    __shared__ __align__(16) unsigned char Ms[128][144];
    const int t = threadIdx.x;
    const int w = t >> 6, lane = t & 63, fr = lane & 15, quad = lane >> 4;
    const int mw = (w >> 1) * 64, nw = (w & 1) * 64;
    f32x4 acc[4][4] = {};

    const int flag = *flagp;
    if (flag) {   // uint8 mask
        const unsigned char* Mb = (const unsigned char*)maskp + ((size_t)b * S + qt * 128) * S + (size_t)kt * 128;
#pragma unroll
        for (int i = 0; i < 4; i++) {
            int idx = t + i * 256;
            int r = idx >> 3, c = (idx & 7) * 16;
            *(int4*)&Ms[r][c] = *(const int4*)(Mb + (size_t)r * S + c);
        }
    } else {      // int32 mask
        const int* Mb = (const int*)maskp + ((size_t)b * S + qt * 128) * S + (size_t)kt * 128;
#pragma unroll
        for (int i = 0; i < 16; i++) {
            int idx = t + i * 256;
            int r = idx >> 5, c = (idx & 31) * 4;
            int4 m = *(const int4*)(Mb + (size_t)r * S + c);
            uchar4 o;
            o.x = (unsigned char)(m.x != 0);
            o.y = (unsigned char)(m.y != 0);
            o.z = (unsigned char)(m.z != 0);
            o.w = (unsigned char)(m.w != 0);
            *(uchar4*)&Ms[r][c] = o;
        }
    }

    for (int k0 = 0; k0 < Dh; k0 += 64) {
        __syncthreads();
#pragma unroll
        for (int i = 0; i < 4; i++) {
            int idx = t + i * 256;                    // 128 rows x 8 (8-col units)
            int r = idx >> 3, c8 = (idx & 7) * 8;
            *(bf16x8*)&As[r][c8] = *(const bf16x8*)(Qb + (size_t)r * Dh + k0 + c8);
            *(bf16x8*)&Bs[r][c8] = *(const bf16x8*)(Kb + (size_t)r * Dh + k0 + c8);
        }
        __syncthreads();
#pragma unroll
        for (int kc = 0; kc < 2; kc++) {
            const int ko = kc * 32 + quad * 8;
            bf16x8 af[4], bf[4];
#pragma unroll
            for (int mi = 0; mi < 4; mi++) af[mi] = *(const bf16x8*)&As[mw + mi * 16 + fr][ko];
#pragma unroll
            for (int ni = 0; ni < 4; ni++) bf[ni] = *(const bf16x8*)&Bs[nw + ni * 16 + fr][ko];
#pragma unroll
            for (int mi = 0; mi < 4; mi++)
#pragma unroll
                for (int ni = 0; ni < 4; ni++)
                    acc[mi][ni] = __builtin_amdgcn_mfma_f32_16x16x32_bf16(af[mi], bf[ni], acc[mi][ni], 0, 0, 0);
        }
    }

    __syncthreads();
    float2* pm = (float2*)&As[0][0];          // reuse As for per-row partials
#pragma unroll
    for (int mi = 0; mi < 4; mi++)
#pragma unroll
        for (int r = 0; r < 4; r++) {
            const int lrow = mw + mi * 16 + quad * 4 + r;
            float s[4];
#pragma unroll
            for (int ni = 0; ni < 4; ni++) {
                const int lcol = nw + ni * 16 + fr;
                float v = acc[mi][ni][r] * SCALE;
                if (Ms[lrow][lcol]) v = NEG_BIG;
                s[ni] = v;
            }
            float mx = fmaxf(fmaxf(s[0], s[1]), fmaxf(s[2], s[3]));
#pragma unroll
            for (int o = 8; o > 0; o >>= 1) mx = fmaxf(mx, __shfl_xor(mx, o, 64));
            float l = __expf(s[0] - mx) + __expf(s[1] - mx) +
                      __expf(s[2] - mx) + __expf(s[3] - mx);
#pragma unroll
            for (int o = 8; o > 0; o >>= 1) l += __shfl_xor(l, o, 64);
            if (fr == 0) pm[lrow * 2 + (w & 1)] = make_float2(mx, l);
        }

    __syncthreads();
    if (t < 128) {
        float2 a = pm[t * 2 + 0], c = pm[t * 2 + 1];
        float M = fmaxf(a.x, c.x);
        float L = a.y * __expf(a.x - M) + c.y * __expf(c.x - M);
        part[((size_t)(b * 16 + kt)) * S + qt * 128 + t] = make_float2(M, L);
    }
}

// ---------------------------------------------------------------------------
// Fold 16 per-kt partials into per-row (M, 1/L). grid: NB*S/256 blocks.
// ---------------------------------------------------------------------------
__global__ __launch_bounds__(256) void reduce_stats(const float2* __restrict__ part,
                                                    float2* __restrict__ stats) {
    const int rid = blockIdx.x * 256 + threadIdx.x;   // [0, NB*S)
    const int b = rid >> 11, row = rid & (S - 1);
    float2 p[16];
    float M = -3.4e38f;
#pragma unroll
    for (int kt = 0; kt < 16; kt++) {
        p[kt] = part[((size_t)(b * 16 + kt)) * S + row];
        M = fmaxf(M, p[kt].x);
    }
    float L = 0.f;
#pragma unroll
    for (int kt = 0; kt < 16; kt++) L += p[kt].y * __expf(p[kt].x - M);
    stats[rid] = make_float2(M, 1.0f / L);
}

// ---------------------------------------------------------------------------
// PASS 2: recompute QK^T per kt-tile, mask, p = exp(s-M)*invL, write final
// attn fp32, pack p->bf16 LDS, PV-MFMA accumulate. One 64-row Q-tile/block,
// grid (32, NB) = 512 blocks (2/CU), 72 KB LDS. K-tile + mask register-
// prefetched one kt ahead. Mask tile aliases Ps (used before P is written).
// ---------------------------------------------------------------------------
__global__ __launch_bounds__(256, 2) void fused_pv(const short* __restrict__ Qbf,
                                                   const short* __restrict__ Kbf,
                                                   const short* __restrict__ Vt,
                                                   const void* __restrict__ maskp,
                                                   const int* __restrict__ flagp,
                                                   const float2* __restrict__ stats,
                                                   float* __restrict__ Attn,
                                                   float* __restrict__ Out) {
    const int qt = blockIdx.x, b = blockIdx.y;
    const short* QbfB = Qbf + ((size_t)b * S + qt * 64) * Dh;
    const short* KbfB = Kbf + (size_t)b * S * Dh;
    const short* VtB  = Vt  + (size_t)b * Dh * S;
    float* AttnB = Attn + ((size_t)b * S + qt * 64) * S;
    float* OutB  = Out  + ((size_t)b * S + qt * 64) * Dh;
    const int flag = *flagp;

    __shared__ short Qs[2][64][72];       // 18 KB
    __shared__ short Ks[2][128][72];      // 36 KB
    __shared__ short Ps[2][64][72];       // 18 KB; first 8 KB doubles as mask tile
    unsigned char (*Ms)[128] = (unsigned char (*)[128]) &Ps[0][0][0];

    const int t = threadIdx.x, w = t >> 6, lane = t & 63, fr = lane & 15, quad = lane >> 4;
    const int mo = (w >> 1) * 32, no = (w & 1) * 64;

    // stage Q tile once (64 x 128 bf16)
#pragma unroll
    for (int i = 0; i < 4; i++) {
        int idx = t + i * 256;
        int r = idx >> 4, c8 = (idx & 15) * 8;
        *(bf16x8*)&Qs[c8 >> 6][r][c8 & 63] = *(const bf16x8*)(QbfB + (size_t)r * Dh + c8);
    }

    // preload per-lane row stats (8 rows each)
    float2 st[2][4];
#pragma unroll
    for (int mi = 0; mi < 2; mi++)
#pragma unroll
        for (int r = 0; r < 4; r++)
            st[mi][r] = stats[(size_t)b * S + qt * 64 + mo + mi * 16 + quad * 4 + r];

    f32x4 acc_o[2][4] = {};

    // prefetch kt=0 K tile (+ u8 mask tile)
    bf16x8 kv[8];
    int4 mreg[2];
#pragma unroll
    for (int i = 0; i < 8; i++) {
        int idx = t + i * 256;
        int r = idx >> 4, c8 = (idx & 15) * 8;
        kv[i] = *(const bf16x8*)(KbfB + (size_t)r * Dh + c8);
    }
    if (flag) {
        const unsigned char* Mb = (const unsigned char*)maskp + ((size_t)b * S + qt * 64) * S;
#pragma unroll
        for (int i = 0; i < 2; i++) {
            int idx = t + i * 256;
            int r = idx >> 3, c16 = (idx & 7) * 16;
            mreg[i] = *(const int4*)(Mb + (size_t)r * S + c16);
        }
    }

    for (int kt = 0; kt < 16; kt++) {
        __syncthreads();   // (a) prev PV done reading Ps/Ks
        // (b) commit prefetched K + mask to LDS
#pragma unroll
        for (int i = 0; i < 8; i++) {
            int idx = t + i * 256;
            int r = idx >> 4, c8 = (idx & 15) * 8;
            *(bf16x8*)&Ks[c8 >> 6][r][c8 & 63] = kv[i];
        }
        if (flag) {
#pragma unroll
            for (int i = 0; i < 2; i++) {
                int idx = t + i * 256;
                int r = idx >> 3, c16 = (idx & 7) * 16;
                *(int4*)&Ms[r][c16] = mreg[i];
            }
        } else {   // int32 mask: load + convert directly (rare path)
            const int* Mb = (const int*)maskp + ((size_t)b * S + qt * 64) * S + (size_t)kt * 128;
#pragma unroll
            for (int i = 0; i < 8; i++) {
                int idx = t + i * 256;
                int r = idx >> 5, c4 = (idx & 31) * 4;
                int4 m = *(const int4*)(Mb + (size_t)r * S + c4);
                uchar4 o;
                o.x = (unsigned char)(m.x != 0);
                o.y = (unsigned char)(m.y != 0);
                o.z = (unsigned char)(m.z != 0);
                o.w = (unsigned char)(m.w != 0);
                *(uchar4*)&Ms[r][c4] = o;
            }
        }
        __syncthreads();   // (d) Ks / Ms visible

        // prefetch next kt while QK-MFMA runs (drained at barrier (f))
        if (kt < 15) {
#pragma unroll
            for (int i = 0; i < 8; i++) {
                int idx = t + i * 256;
                int r = idx >> 4, c8 = (idx & 15) * 8;
                kv[i] = *(const bf16x8*)(KbfB + (size_t)((kt + 1) * 128 + r) * Dh + c8);
            }
            if (flag) {
                const unsigned char* Mb = (const unsigned char*)maskp + ((size_t)b * S + qt * 64) * S + (size_t)(kt + 1) * 128;
#pragma unroll
                for (int i = 0; i < 2; i++) {
                    int idx = t + i * 256;
                    int r = idx >> 3, c16 = (idx & 7) * 16;
                    mreg[i] = *(const int4*)(Mb + (size_t)r * S + c16);
                }
            }
        }

        // QK^T: S-tile 64x128, wave quadrant 32x64
        f32x4 acc_s[2][4] = {};
#pragma unroll
        for (int ks = 0; ks < 4; ks++) {
            const int h = ks >> 1, o = (ks & 1) * 32 + quad * 8;
            bf16x8 af[2], bf[4];
#pragma unroll
            for (int mi = 0; mi < 2; mi++) af[mi] = *(const bf16x8*)&Qs[h][mo + mi * 16 + fr][o];
#pragma unroll
            for (int ni = 0; ni < 4; ni++) bf[ni] = *(const bf16x8*)&Ks[h][no + ni * 16 + fr][o];
#pragma unroll
            for (int mi = 0; mi < 2; mi++)
#pragma unroll
                for (int ni = 0; ni < 4; ni++)
                    acc_s[mi][ni] = __builtin_amdgcn_mfma_f32_16x16x32_bf16(af[mi], bf[ni], acc_s[mi][ni], 0, 0, 0);
        }

        // epilogue: scale, mask, p = exp(s-M)*invL, write final attn, pack bf16
        short ps[2][4][4];
#pragma unroll
        for (int mi = 0; mi < 2; mi++)
#pragma unroll
            for (int ni = 0; ni < 4; ni++)
#pragma unroll
                for (int r = 0; r < 4; r++) {
                    const int row = mo + mi * 16 + quad * 4 + r;
                    const int col = no + ni * 16 + fr;
                    float v = acc_s[mi][ni][r] * SCALE;
                    if (Ms[row][col]) v = NEG_BIG;
                    float p = __expf(v - st[mi][r].x) * st[mi][r].y;
                    AttnB[(size_t)row * S + kt * 128 + col] = p;
                    ps[mi][ni][r] = f2bf(p);
                }
        __syncthreads();   // (f) all mask reads done before Ps overwrite
#pragma unroll
        for (int mi = 0; mi < 2; mi++)
#pragma unroll
            for (int ni = 0; ni < 4; ni++)
#pragma unroll
                for (int r = 0; r < 4; r++) {
                    const int row = mo + mi * 16 + quad * 4 + r;
                    const int col = no + ni * 16 + fr;
                    Ps[col >> 6][row][col & 63] = ps[mi][ni][r];
                }
        __syncthreads();   // (h) Ps visible

        // PV: out-tile 64x128, same quadrant mapping; B from global Vt (L2-hot)
#pragma unroll
        for (int ks = 0; ks < 4; ks++) {
            const int h = ks >> 1, o = (ks & 1) * 32 + quad * 8;
            bf16x8 paf[2], pbf[4];
#pragma unroll
            for (int mi = 0; mi < 2; mi++) paf[mi] = *(const bf16x8*)&Ps[h][mo + mi * 16 + fr][o];
#pragma unroll
            for (int ni = 0; ni < 4; ni++)
                pbf[ni] = *(const bf16x8*)(VtB + (size_t)(no + ni * 16 + fr) * S + kt * 128 + ks * 32 + quad * 8);
#pragma unroll
            for (int mi = 0; mi < 2; mi++)
#pragma unroll
                for (int ni = 0; ni < 4; ni++)
                    acc_o[mi][ni] = __builtin_amdgcn_mfma_f32_16x16x32_bf16(paf[mi], pbf[ni], acc_o[mi][ni], 0, 0, 0);
        }
    }

#pragma unroll
    for (int mi = 0; mi < 2; mi++)
#pragma unroll
        for (int ni = 0; ni < 4; ni++)
#pragma unroll
            for (int r = 0; r < 4; r++) {
                const int row = mo + mi * 16 + quad * 4 + r;
                const int col = no + ni * 16 + fr;
                OutB[(size_t)row * Dh + col] = acc_o[mi][ni][r];
            }
}

// ===========================================================================
// FALLBACK PATH (verified round-2 kernels, used when ws is too small)
// ===========================================================================
__global__ __launch_bounds__(256, 2) void qk_kernel(const float* __restrict__ Q,
                                                    const float* __restrict__ Km,
                                                    float* __restrict__ Sc,
                                                    const void* __restrict__ maskp,
                                                    const int* __restrict__ flagp,
                                                    float2* __restrict__ part,
                                                    const int fuse) {
    const int kt = blockIdx.x, qt = blockIdx.y, b = blockIdx.z;
    const float* Qb = Q + ((size_t)b * S + qt * 128) * Dh;
    const float* Kb = Km + ((size_t)b * S + kt * 128) * Dh;
    __shared__ short As[128][72];
    __shared__ short Bs[128][72];
    __shared__ __align__(16) unsigned char Ms[128][144];
    const int t = threadIdx.x;
    const int w = t >> 6, lane = t & 63, fr = lane & 15, quad = lane >> 4;
    const int mw = (w >> 1) * 64, nw = (w & 1) * 64;
    f32x4 acc[4][4] = {};

    if (fuse) {
        const int flag = *flagp;
        if (flag) {
            const unsigned char* Mb = (const unsigned char*)maskp + ((size_t)b * S + qt * 128) * S + (size_t)kt * 128;
#pragma unroll
            for (int i = 0; i < 4; i++) {
                int idx = t + i * 256;
                int r = idx >> 3, c = (idx & 7) * 16;
                *(int4*)&Ms[r][c] = *(const int4*)(Mb + (size_t)r * S + c);
            }
        } else {
            const int* Mb = (const int*)maskp + ((size_t)b * S + qt * 128) * S + (size_t)kt * 128;
#pragma unroll
            for (int i = 0; i < 16; i++) {
                int idx = t + i * 256;
                int r = idx >> 5, c = (idx & 31) * 4;
                int4 m = *(const int4*)(Mb + (size_t)r * S + c);
                uchar4 o;
                o.x = (unsigned char)(m.x != 0);
                o.y = (unsigned char)(m.y != 0);
                o.z = (unsigned char)(m.z != 0);
                o.w = (unsigned char)(m.w != 0);
                *(uchar4*)&Ms[r][c] = o;
            }
        }
    }

    for (int k0 = 0; k0 < Dh; k0 += 64) {
        __syncthreads();
#pragma unroll
        for (int i = 0; i < 8; i++) {
            int idx = t + i * 256;
            int r = idx >> 4, c = (idx & 15) << 2;
            float4 qv = *(const float4*)(Qb + r * Dh + k0 + c);
            float4 kv = *(const float4*)(Kb + r * Dh + k0 + c);
            *(s16x4*)&As[r][c] = pack4(qv);
            *(s16x4*)&Bs[r][c] = pack4(kv);
        }
        __syncthreads();
#pragma unroll
        for (int kc = 0; kc < 2; kc++) {
            const int ko = kc * 32 + quad * 8;
            bf16x8 af[4], bf[4];
#pragma unroll
            for (int mi = 0; mi < 4; mi++) af[mi] = *(const bf16x8*)&As[mw + mi * 16 + fr][ko];
#pragma unroll
            for (int ni = 0; ni < 4; ni++) bf[ni] = *(const bf16x8*)&Bs[nw + ni * 16 + fr][ko];
#pragma unroll
            for (int mi = 0; mi < 4; mi++)
#pragma unroll
                for (int ni = 0; ni < 4; ni++)
                    acc[mi][ni] = __builtin_amdgcn_mfma_f32_16x16x32_bf16(af[mi], bf[ni], acc[mi][ni], 0, 0, 0);
        }
    }

    __syncthreads();
    float2* pm = (float2*)&As[0][0];
    float* ScB = Sc + (size_t)b * S * S;
#pragma unroll
    for (int mi = 0; mi < 4; mi++)
#pragma unroll
        for (int r = 0; r < 4; r++) {
            const int lrow = mw + mi * 16 + quad * 4 + r;
            const size_t grow = (size_t)(qt * 128 + lrow);
            float s[4];
#pragma unroll
            for (int ni = 0; ni < 4; ni++) {
                const int lcol = nw + ni * 16 + fr;
                float v = acc[mi][ni][r] * SCALE;
                if (fuse && Ms[lrow][lcol]) v = NEG_BIG;
                s[ni] = v;
                ScB[grow * S + kt * 128 + lcol] = v;
            }
            if (fuse) {
                float mx = fmaxf(fmaxf(s[0], s[1]), fmaxf(s[2], s[3]));
#pragma unroll
                for (int o = 8; o > 0; o >>= 1) mx = fmaxf(mx, __shfl_xor(mx, o, 64));
                float l = __expf(s[0] - mx) + __expf(s[1] - mx) +
                          __expf(s[2] - mx) + __expf(s[3] - mx);
#pragma unroll
                for (int o = 8; o > 0; o >>= 1) l += __shfl_xor(l, o, 64);
                if (fr == 0) pm[lrow * 2 + (w & 1)] = make_float2(mx, l);
            }
        }

    if (fuse) {
        __syncthreads();
        if (t < 128) {
            float2 a = pm[t * 2 + 0], c = pm[t * 2 + 1];
            float M = fmaxf(a.x, c.x);
            float L = a.y * __expf(a.x - M) + c.y * __expf(c.x - M);
            part[((size_t)(b * 16 + kt)) * S + qt * 128 + t] = make_float2(M, L);
        }
    }
}

__global__ __launch_bounds__(256) void softmax_kernel(float* __restrict__ Sc,
                                                      const void* __restrict__ maskp,
                                                      const int* __restrict__ flagp) {
    const int b = blockIdx.y;
    const int w = threadIdx.x >> 6, lane = threadIdx.x & 63;
    const int row = blockIdx.x * 4 + w;
    float* R = Sc + ((size_t)b * S + row) * S;
    float4* R4 = (float4*)R;
    const int flag = flagp ? *flagp : 0;

    float sv[32];
    if (flag) {
        const uchar4* M4 = (const uchar4*)((const unsigned char*)maskp + ((size_t)b * S + row) * S);
#pragma unroll
        for (int j = 0; j < 8; j++) {
            float4 v = R4[lane + 64 * j];
            uchar4 m = M4[lane + 64 * j];
            sv[4 * j + 0] = m.x ? NEG_BIG : v.x;
            sv[4 * j + 1] = m.y ? NEG_BIG : v.y;
            sv[4 * j + 2] = m.z ? NEG_BIG : v.z;
            sv[4 * j + 3] = m.w ? NEG_BIG : v.w;
        }
    } else {
        const int4* M4 = (const int4*)((const int*)maskp + ((size_t)b * S + row) * S);
#pragma unroll
        for (int j = 0; j < 8; j++) {
            float4 v = R4[lane + 64 * j];
            int4 m = M4[lane + 64 * j];
            sv[4 * j + 0] = m.x ? NEG_BIG : v.x;
            sv[4 * j + 1] = m.y ? NEG_BIG : v.y;
            sv[4 * j + 2] = m.z ? NEG_BIG : v.z;
            sv[4 * j + 3] = m.w ? NEG_BIG : v.w;
        }
    }

    float mx = sv[0];
#pragma unroll
    for (int i = 1; i < 32; i++) mx = fmaxf(mx, sv[i]);
    for (int o = 32; o > 0; o >>= 1) mx = fmaxf(mx, __shfl_xor(mx, o, 64));

    float sum = 0.f;
#pragma unroll
    for (int i = 0; i < 32; i++) {
        sv[i] = __expf(sv[i] - mx);
        sum += sv[i];
    }
    for (int o = 32; o > 0; o >>= 1) sum += __shfl_xor(sum, o, 64);
    const float inv = 1.0f / sum;

#pragma unroll
    for (int j = 0; j < 8; j++) {
        float4 p;
        p.x = sv[4 * j + 0] * inv;
        p.y = sv[4 * j + 1] * inv;
        p.z = sv[4 * j + 2] * inv;
        p.w = sv[4 * j + 3] * inv;
        R4[lane + 64 * j] = p;
    }
}

__global__ __launch_bounds__(256, 2) void pv_kernel(float* __restrict__ Sc,
                                                    const float* __restrict__ V,
                                                    const short* __restrict__ Vt,
                                                    const int useVt,
                                                    float* __restrict__ Out,
                                                    const float2* __restrict__ stats,
                                                    const int fuse) {
    const int mt = blockIdx.x, b = blockIdx.y;
    float* ScB = Sc + (size_t)b * S * S + (size_t)mt * 64 * S;
    const float* Vb = V + (size_t)b * S * Dh;
    const short* VtB = Vt + (size_t)b * Dh * S;
    float* OutB = Out + ((size_t)b * S + mt * 64) * Dh;
    __shared__ short As[64][72];
    __shared__ float2 sstat[64];
    const int t = threadIdx.x, w = t >> 6, lane = t & 63, fr = lane & 15, quad = lane >> 4;
    const int mw = (w >> 1) * 32, nw = (w & 1) * 64;
    f32x4 acc[2][4] = {};

    if (fuse && t < 64) sstat[t] = stats[(size_t)b * S + mt * 64 + t];

    for (int k0 = 0; k0 < S; k0 += 64) {
        __syncthreads();
#pragma unroll
        for (int i = 0; i < 4; i++) {
            int idx = t + i * 256;
            int r = idx >> 4, c = (idx & 15) << 2;
            float4 v = *(const float4*)(ScB + (size_t)r * S + k0 + c);
            if (fuse) {
                float2 stv = sstat[r];
                v.x = __expf(v.x - stv.x) * stv.y;
                v.y = __expf(v.y - stv.x) * stv.y;
                v.z = __expf(v.z - stv.x) * stv.y;
                v.w = __expf(v.w - stv.x) * stv.y;
                *(float4*)(ScB + (size_t)r * S + k0 + c) = v;
            }
            *(s16x4*)&As[r][c] = pack4(v);
        }
        __syncthreads();
#pragma unroll
        for (int kc = 0; kc < 2; kc++) {
            const int ko = kc * 32 + quad * 8;
            bf16x8 af[2], bf[4];
#pragma unroll
            for (int mi = 0; mi < 2; mi++) af[mi] = *(const bf16x8*)&As[mw + mi * 16 + fr][ko];
            if (useVt) {
#pragma unroll
                for (int ni = 0; ni < 4; ni++)
                    bf[ni] = *(const bf16x8*)(VtB + (size_t)(nw + ni * 16 + fr) * S + k0 + ko);
            } else {
#pragma unroll
                for (int ni = 0; ni < 4; ni++) {
                    int n = nw + ni * 16 + fr;
#pragma unroll
                    for (int j = 0; j < 8; j++) bf[ni][j] = f2bf(Vb[(size_t)(k0 + ko + j) * Dh + n]);
                }
            }
#pragma unroll
            for (int mi = 0; mi < 2; mi++)
#pragma unroll
                for (int ni = 0; ni < 4; ni++)
                    acc[mi][ni] = __builtin_amdgcn_mfma_f32_16x16x32_bf16(af[mi], bf[ni], acc[mi][ni], 0, 0, 0);
        }
    }

#pragma unroll
    for (int mi = 0; mi < 2; mi++)
#pragma unroll
        for (int ni = 0; ni < 4; ni++)
#pragma unroll
            for (int r = 0; r < 4; r++) {
                int row = mw + mi * 16 + quad * 4 + r;
                int col = nw + ni * 16 + fr;
                OutB[(size_t)row * Dh + col] = acc[mi][ni][r];
            }
}

extern "C" void kernel_launch(void* const* d_in, const int* in_sizes, int n_in,
                              void* d_out, int out_size, void* d_ws, size_t ws_size,
                              hipStream_t stream) {
    const float* Q = (const float*)d_in[0];
    const float* Km = (const float*)d_in[1];
    const float* V = (const float*)d_in[2];
    const void* M = d_in[3];
    float* out = (float*)d_out;
    float* attn = out + OUT_ELEMS;

    const size_t VT_BYTES   = (size_t)NB * Dh * S * sizeof(short);   // 8 MB
    const size_t QBF_BYTES  = (size_t)NB * S * Dh * sizeof(short);   // 8 MB
    const size_t KBF_BYTES  = QBF_BYTES;                             // 8 MB
    const size_t STATS_BYTES = (size_t)NB * S * sizeof(float2);      // 256 KB
    const size_t REQ_NEW = VT_BYTES + QBF_BYTES + KBF_BYTES + STATS_BYTES + 64;

    // Per-(row, kt) softmax partials live in the `out` region of d_out (16 MB;
    // partials use 4 MB); consumed by reduce_stats before any kernel writes out.
    float2* part = (float2*)d_out;

    if (ws_size >= REQ_NEW) {
        short* Vt   = (short*)d_ws;
        short* Qbf  = (short*)((char*)d_ws + VT_BYTES);
        short* Kbf  = (short*)((char*)d_ws + VT_BYTES + QBF_BYTES);
        float2* stats = (float2*)((char*)d_ws + VT_BYTES + QBF_BYTES + KBF_BYTES);
        int* flag = (int*)((char*)d_ws + VT_BYTES + QBF_BYTES + KBF_BYTES + STATS_BYTES);

        detect_mask<<<1, 256, 0, stream>>>((const unsigned char*)M, flag);
        transpose_v<<<dim3(32, NB), 256, 0, stream>>>(V, Vt);
        cvt_bf16<<<2048, 256, 0, stream>>>(Q, Qbf);
        cvt_bf16<<<2048, 256, 0, stream>>>(Km, Kbf);
        qk_stats<<<dim3(16, 16, NB), 256, 0, stream>>>(Qbf, Kbf, M, flag, part);
        reduce_stats<<<dim3((NB * S) / 256), 256, 0, stream>>>(part, stats);
        fused_pv<<<dim3(32, NB), 256, 0, stream>>>(Qbf, Kbf, Vt, M, flag, stats, attn, out);
        return;
    }

    // ---------------- fallback: verified round-2 path ----------------
    int useVt = 0, fuse = 0;
    short* Vt = nullptr;
    float2* stats = nullptr;
    int* flag = nullptr;

    if (ws_size >= VT_BYTES + STATS_BYTES + 64) {
        useVt = 1; fuse = 1;
        Vt = (short*)d_ws;
        stats = (float2*)((char*)d_ws + VT_BYTES);
        flag = (int*)((char*)d_ws + VT_BYTES + STATS_BYTES);
    } else if (ws_size >= VT_BYTES + 64) {
        useVt = 1;
        Vt = (short*)d_ws;
        flag = (int*)((char*)d_ws + VT_BYTES);
    } else if (ws_size >= 64) {
        flag = (int*)d_ws;
    }

    if (flag) detect_mask<<<1, 256, 0, stream>>>((const unsigned char*)M, flag);
    if (useVt) transpose_v<<<dim3(32, NB), 256, 0, stream>>>(V, Vt);

    qk_kernel<<<dim3(16, 16, NB), 256, 0, stream>>>(Q, Km, attn, M, flag, part, fuse);

    if (fuse) {
        reduce_stats<<<dim3((NB * S) / 256), 256, 0, stream>>>(part, stats);
        pv_kernel<<<dim3(32, NB), 256, 0, stream>>>(attn, V, Vt, useVt, out, stats, 1);
    } else {
        softmax_kernel<<<dim3(512, NB), 256, 0, stream>>>(attn, M, flag);
        pv_kernel<<<dim3(32, NB), 256, 0, stream>>>(attn, V, Vt, useVt, out, nullptr, 0);
    }
}

// Round 4
// 656.268 us; speedup vs baseline: 1.1625x; 1.0537x over previous
//
#include <hip/hip_runtime.h>

#define S 2048
#define Dh 128
#define NB 16
#define OUT_ELEMS ((size_t)NB * S * Dh)   // 4194304 floats (16 MB region before attn)
#define NEG_BIG -1.0e9f
#define SCALE 0.08838834764831845f        // 1/sqrt(128)

typedef __attribute__((ext_vector_type(8))) short bf16x8;
typedef __attribute__((ext_vector_type(4))) float f32x4;
typedef __attribute__((ext_vector_type(4))) short s16x4;

__device__ __forceinline__ short f2bf(float x) {
    unsigned u = __float_as_uint(x);
    u += 0x7fffu + ((u >> 16) & 1u);      // RNE truncate to bf16 (no NaN inputs here)
    return (short)(u >> 16);
}

__device__ __forceinline__ s16x4 pack4(float4 v) {
    s16x4 r;
    r.x = f2bf(v.x); r.y = f2bf(v.y); r.z = f2bf(v.z); r.w = f2bf(v.w);
    return r;
}

// ---------------------------------------------------------------------------
// Mask dtype detection: int32-encoded bool has bytes 1..3 of each word == 0.
// flag = 1 -> uint8 mask, flag = 0 -> int32 mask.
// ---------------------------------------------------------------------------
__global__ void detect_mask(const unsigned char* __restrict__ m, int* __restrict__ flag) {
    __shared__ int any;
    if (threadIdx.x == 0) any = 0;
    __syncthreads();
    int t = threadIdx.x;
    unsigned char v = (unsigned char)(m[t * 4 + 1] | m[t * 4 + 2] | m[t * 4 + 3]);
    if (v) atomicOr(&any, 1);
    __syncthreads();
    if (t == 0) *flag = any;
}

// ---------------------------------------------------------------------------
// V [b][k][n] fp32  ->  Vt [b][n][k] bf16 (k contiguous for MFMA B-fragments)
// ---------------------------------------------------------------------------
__global__ __launch_bounds__(256) void transpose_v(const float* __restrict__ V,
                                                   short* __restrict__ Vt) {
    const int kb = blockIdx.x, b = blockIdx.y;
    const float* Vb = V + ((size_t)b * S + kb * 64) * Dh;
    short* VtB = Vt + (size_t)b * Dh * S;
    __shared__ float Ls[64][132];
    const int t = threadIdx.x;
#pragma unroll
    for (int i = 0; i < 8; i++) {
        int idx = t + i * 256;
        int r = idx >> 5, c = (idx & 31) << 2;
        *(float4*)&Ls[r][c] = *(const float4*)(Vb + r * Dh + c);
    }
    __syncthreads();
#pragma unroll
    for (int i = 0; i < 8; i++) {
        int idx = t + i * 256;
        int n = idx >> 4, kc = (idx & 15) << 2;
        s16x4 o;
        o.x = f2bf(Ls[kc + 0][n]);
        o.y = f2bf(Ls[kc + 1][n]);
        o.z = f2bf(Ls[kc + 2][n]);
        o.w = f2bf(Ls[kc + 3][n]);
        *(s16x4*)(VtB + (size_t)n * S + kb * 64 + kc) = o;
    }
}

// ---------------------------------------------------------------------------
// fp32 -> bf16 row-major copy (Q and K pre-conversion).
// ---------------------------------------------------------------------------
__global__ __launch_bounds__(256) void cvt_bf16(const float* __restrict__ in,
                                                short* __restrict__ out) {
    const size_t n4 = (size_t)NB * S * Dh / 4;
    for (size_t i = (size_t)blockIdx.x * 256 + threadIdx.x; i < n4; i += (size_t)gridDim.x * 256) {
        float4 v = ((const float4*)in)[i];
        ((s16x4*)out)[i] = pack4(v);
    }
}

// ---------------------------------------------------------------------------
// PASS 1 (flash): per 64-row Q-tile, loop kt: QK -> mask -> online softmax
// (running m,l; O rescale) -> P bf16 -> PV accumulate. Writes out (16 MB)
// + final per-row stats (M, 1/L). No attn write, no precomputed stats.
// Rows-per-wave layout: wave w owns rows mo=w*16 .. mo+15, all 128 cols, so
// row reductions are in-wave shfl over the 16-lane fr group.
// grid: 512 1-D blocks with XCD-grouped (b,qt) decode; 80 KB LDS, 2 blk/CU.
// ---------------------------------------------------------------------------
__global__ __launch_bounds__(256, 2) void flash_pv(const short* __restrict__ Qbf,
                                                   const short* __restrict__ Kbf,
                                                   const short* __restrict__ Vt,
                                                   const void* __restrict__ maskp,
                                                   const int* __restrict__ flagp,
                                                   float2* __restrict__ stats,
                                                   float* __restrict__ Out) {
    // bid = k*8 + xcd, xcd = b>>1, k = (b&1)*32 + qt  (bijective; 2 batches/XCD)
    const int bid = blockIdx.x;
    const int xcd = bid & 7, kk = bid >> 3;
    const int b = xcd * 2 + (kk >> 5), qt = kk & 31;

    const short* QbfB = Qbf + ((size_t)b * S + qt * 64) * Dh;
    const short* KbfB = Kbf + (size_t)b * S * Dh;
    const short* VtB  = Vt  + (size_t)b * Dh * S;
    float* OutB = Out + ((size_t)b * S + qt * 64) * Dh;
    const int flag = *flagp;

    __shared__ short Qs[2][64][72];                      // 18 KB
    __shared__ short Ks[2][128][72];                     // 36 KB
    __shared__ short Ps[2][64][72];                      // 18 KB
    __shared__ __align__(16) unsigned char Msk[64][128]; // 8 KB  (total 80 KB)

    const int t = threadIdx.x, w = t >> 6, lane = t & 63, fr = lane & 15, quad = lane >> 4;
    const int mo = w * 16;

    // stage Q tile once (64 x 128 bf16)
#pragma unroll
    for (int i = 0; i < 4; i++) {
        int idx = t + i * 256;
        int r = idx >> 4, c8 = (idx & 15) * 8;
        *(bf16x8*)&Qs[c8 >> 6][r][c8 & 63] = *(const bf16x8*)(QbfB + (size_t)r * Dh + c8);
    }

    float m[4], l[4];
#pragma unroll
    for (int r = 0; r < 4; r++) { m[r] = -3.4e38f; l[r] = 0.f; }
    f32x4 acc_o[8] = {};

    // prefetch kt=0 K tile (+ u8 mask tile)
    bf16x8 kv[8];
    int4 mreg[2];
#pragma unroll
    for (int i = 0; i < 8; i++) {
        int idx = t + i * 256;
        int r = idx >> 4, c8 = (idx & 15) * 8;
        kv[i] = *(const bf16x8*)(KbfB + (size_t)r * Dh + c8);
    }
    if (flag) {
        const unsigned char* Mb = (const unsigned char*)maskp + ((size_t)b * S + qt * 64) * S;
#pragma unroll
        for (int i = 0; i < 2; i++) {
            int idx = t + i * 256;
            int r = idx >> 3, c16 = (idx & 7) * 16;
            mreg[i] = *(const int4*)(Mb + (size_t)r * S + c16);
        }
    }

    for (int kt = 0; kt < 16; kt++) {
        __syncthreads();   // (a) prev iteration's QK/PV reads of Ks/Msk/Ps done
#pragma unroll
        for (int i = 0; i < 8; i++) {
            int idx = t + i * 256;
            int r = idx >> 4, c8 = (idx & 15) * 8;
            *(bf16x8*)&Ks[c8 >> 6][r][c8 & 63] = kv[i];
        }
        if (flag) {
#pragma unroll
            for (int i = 0; i < 2; i++) {
                int idx = t + i * 256;
                int r = idx >> 3, c16 = (idx & 7) * 16;
                *(int4*)&Msk[r][c16] = mreg[i];
            }
        } else {   // int32 mask: load + convert directly (rare path)
            const int* Mb = (const int*)maskp + ((size_t)b * S + qt * 64) * S + (size_t)kt * 128;
#pragma unroll
            for (int i = 0; i < 8; i++) {
                int idx = t + i * 256;
                int r = idx >> 5, c4 = (idx & 31) * 4;
                int4 mv = *(const int4*)(Mb + (size_t)r * S + c4);
                uchar4 o;
                o.x = (unsigned char)(mv.x != 0);
                o.y = (unsigned char)(mv.y != 0);
                o.z = (unsigned char)(mv.z != 0);
                o.w = (unsigned char)(mv.w != 0);
                *(uchar4*)&Msk[r][c4] = o;
            }
        }
        __syncthreads();   // (b) Ks / Msk visible

        // prefetch next kt while QK runs
        if (kt < 15) {
#pragma unroll
            for (int i = 0; i < 8; i++) {
                int idx = t + i * 256;
                int r = idx >> 4, c8 = (idx & 15) * 8;
                kv[i] = *(const bf16x8*)(KbfB + (size_t)((kt + 1) * 128 + r) * Dh + c8);
            }
            if (flag) {
                const unsigned char* Mb = (const unsigned char*)maskp + ((size_t)b * S + qt * 64) * S + (size_t)(kt + 1) * 128;
#pragma unroll
                for (int i = 0; i < 2; i++) {
                    int idx = t + i * 256;
                    int r = idx >> 3, c16 = (idx & 7) * 16;
                    mreg[i] = *(const int4*)(Mb + (size_t)r * S + c16);
                }
            }
        }

        // QK^T: wave rows mo..mo+15 x 128 cols
        f32x4 acc_s[8] = {};
#pragma unroll
        for (int ks = 0; ks < 4; ks++) {
            const int h = ks >> 1, o = (ks & 1) * 32 + quad * 8;
            bf16x8 af = *(const bf16x8*)&Qs[h][mo + fr][o];
            bf16x8 bfv[8];
#pragma unroll
            for (int ni = 0; ni < 8; ni++) bfv[ni] = *(const bf16x8*)&Ks[h][ni * 16 + fr][o];
#pragma unroll
            for (int ni = 0; ni < 8; ni++)
                acc_s[ni] = __builtin_amdgcn_mfma_f32_16x16x32_bf16(af, bfv[ni], acc_s[ni], 0, 0, 0);
        }

        // online-softmax epilogue, per owned row
#pragma unroll
        for (int r = 0; r < 4; r++) {
            const int row = mo + quad * 4 + r;
            float s[8];
#pragma unroll
            for (int ni = 0; ni < 8; ni++) {
                float v = acc_s[ni][r] * SCALE;
                if (Msk[row][ni * 16 + fr]) v = NEG_BIG;
                s[ni] = v;
            }
            float mx = s[0];
#pragma unroll
            for (int ni = 1; ni < 8; ni++) mx = fmaxf(mx, s[ni]);
#pragma unroll
            for (int o = 8; o > 0; o >>= 1) mx = fmaxf(mx, __shfl_xor(mx, o, 64));
            const float mn = fmaxf(m[r], mx);
            const float f = __expf(m[r] - mn);   // 0 on first tile (m = -3.4e38)
            float p[8], lt = 0.f;
#pragma unroll
            for (int ni = 0; ni < 8; ni++) { p[ni] = __expf(s[ni] - mn); lt += p[ni]; }
#pragma unroll
            for (int o = 8; o > 0; o >>= 1) lt += __shfl_xor(lt, o, 64);
            l[r] = l[r] * f + lt;
            m[r] = mn;
#pragma unroll
            for (int ni = 0; ni < 8; ni++) acc_o[ni][r] *= f;
#pragma unroll
            for (int ni = 0; ni < 8; ni++) {
                const int col = ni * 16 + fr;
                Ps[col >> 6][row][col & 63] = f2bf(p[ni]);
            }
        }
        __syncthreads();   // (c) Ps visible

        // PV: out 64x128; B-fragments from global Vt (L2-resident per XCD)
#pragma unroll
        for (int ks = 0; ks < 4; ks++) {
            const int h = ks >> 1, o = (ks & 1) * 32 + quad * 8;
            bf16x8 paf = *(const bf16x8*)&Ps[h][mo + fr][o];
            bf16x8 pb[8];
#pragma unroll
            for (int ni = 0; ni < 8; ni++)
                pb[ni] = *(const bf16x8*)(VtB + (size_t)(ni * 16 + fr) * S + kt * 128 + ks * 32 + quad * 8);
#pragma unroll
            for (int ni = 0; ni < 8; ni++)
                acc_o[ni] = __builtin_amdgcn_mfma_f32_16x16x32_bf16(paf, pb[ni], acc_o[ni], 0, 0, 0);
        }
    }

    float invl[4];
#pragma unroll
    for (int r = 0; r < 4; r++) invl[r] = 1.0f / l[r];
#pragma unroll
    for (int ni = 0; ni < 8; ni++)
#pragma unroll
        for (int r = 0; r < 4; r++) {
            const int row = mo + quad * 4 + r;
            OutB[(size_t)row * Dh + ni * 16 + fr] = acc_o[ni][r] * invl[r];
        }
    if (fr == 0) {
#pragma unroll
        for (int r = 0; r < 4; r++)
            stats[(size_t)b * S + qt * 64 + mo + quad * 4 + r] = make_float2(m[r], invl[r]);
    }
}

// ---------------------------------------------------------------------------
// PASS 2: fully-parallel attn writer. 128x128 tiles, recompute QK^T with the
// SAME accumulation order as flash_pv, mask, p = exp(s-M)*invL, store attn.
// grid: 4096 1-D blocks with XCD-grouped (b,qt,kt) decode.
// ---------------------------------------------------------------------------
__global__ __launch_bounds__(256, 2) void attn_write(const short* __restrict__ Qbf,
                                                     const short* __restrict__ Kbf,
                                                     const void* __restrict__ maskp,
                                                     const int* __restrict__ flagp,
                                                     const float2* __restrict__ stats,
                                                     float* __restrict__ Attn) {
    // bid = k*8 + xcd, xcd = b>>1, k = (b&1)*256 + qt*16 + kt  (bijective)
    const int bid = blockIdx.x;
    const int xcd = bid & 7, kk = bid >> 3;
    const int b = xcd * 2 + (kk >> 8), rem = kk & 255, qt = rem >> 4, kt = rem & 15;

    const short* Qb = Qbf + ((size_t)b * S + qt * 128) * Dh;
    const short* Kb = Kbf + ((size_t)b * S + kt * 128) * Dh;
    __shared__ short As[128][72];
    __shared__ short Bs[128][72];
    __shared__ __align__(16) unsigned char Ms[128][144];
    const int t = threadIdx.x;
    const int w = t >> 6, lane = t & 63, fr = lane & 15, quad = lane >> 4;
    const int mw = (w >> 1) * 64, nw = (w & 1) * 64;
    f32x4 acc[4][4] = {};

    const int flag = *flagp;
    if (flag) {   // uint8 mask
        const unsigned char* Mb = (const unsigned char*)maskp + ((size_t)b * S + qt * 128) * S + (size_t)kt * 128;
#pragma unroll
        for (int i = 0; i < 4; i++) {
            int idx = t + i * 256;
            int r = idx >> 3, c = (idx & 7) * 16;
            *(int4*)&Ms[r][c] = *(const int4*)(Mb + (size_t)r * S + c);
        }
    } else {      // int32 mask
        const int* Mb = (const int*)maskp + ((size_t)b * S + qt * 128) * S + (size_t)kt * 128;
#pragma unroll
        for (int i = 0; i < 16; i++) {
            int idx = t + i * 256;
            int r = idx >> 5, c = (idx & 31) * 4;
            int4 mv = *(const int4*)(Mb + (size_t)r * S + c);
            uchar4 o;
            o.x = (unsigned char)(mv.x != 0);
            o.y = (unsigned char)(mv.y != 0);
            o.z = (unsigned char)(mv.z != 0);
            o.w = (unsigned char)(mv.w != 0);
            *(uchar4*)&Ms[r][c] = o;
        }
    }

    // preload row stats (overlaps with staging latency)
    float2 st[4][4];
#pragma unroll
    for (int mi = 0; mi < 4; mi++)
#pragma unroll
        for (int r = 0; r < 4; r++)
            st[mi][r] = stats[(size_t)b * S + qt * 128 + mw + mi * 16 + quad * 4 + r];

    for (int k0 = 0; k0 < Dh; k0 += 64) {
        __syncthreads();
#pragma unroll
        for (int i = 0; i < 4; i++) {
            int idx = t + i * 256;
            int r = idx >> 3, c8 = (idx & 7) * 8;
            *(bf16x8*)&As[r][c8] = *(const bf16x8*)(Qb + (size_t)r * Dh + k0 + c8);
            *(bf16x8*)&Bs[r][c8] = *(const bf16x8*)(Kb + (size_t)r * Dh + k0 + c8);
        }
        __syncthreads();
#pragma unroll
        for (int kc = 0; kc < 2; kc++) {
            const int ko = kc * 32 + quad * 8;
            bf16x8 af[4], bf[4];
#pragma unroll
            for (int mi = 0; mi < 4; mi++) af[mi] = *(const bf16x8*)&As[mw + mi * 16 + fr][ko];
#pragma unroll
            for (int ni = 0; ni < 4; ni++) bf[ni] = *(const bf16x8*)&Bs[nw + ni * 16 + fr][ko];
#pragma unroll
            for (int mi = 0; mi < 4; mi++)
#pragma unroll
                for (int ni = 0; ni < 4; ni++)
                    acc[mi][ni] = __builtin_amdgcn_mfma_f32_16x16x32_bf16(af[mi], bf[ni], acc[mi][ni], 0, 0, 0);
        }
    }

    float* AttnB = Attn + (size_t)b * S * S;
#pragma unroll
    for (int mi = 0; mi < 4; mi++)
#pragma unroll
        for (int ni = 0; ni < 4; ni++)
#pragma unroll
            for (int r = 0; r < 4; r++) {
                const int lrow = mw + mi * 16 + quad * 4 + r;
                const int lcol = nw + ni * 16 + fr;
                float v = acc[mi][ni][r] * SCALE;
                if (Ms[lrow][lcol]) v = NEG_BIG;
                const float p = __expf(v - st[mi][r].x) * st[mi][r].y;
                AttnB[(size_t)(qt * 128 + lrow) * S + kt * 128 + lcol] = p;
            }
}

// ===========================================================================
// FALLBACK PATH (verified round-2 kernels, used when ws is too small)
// ===========================================================================
__global__ __launch_bounds__(256) void reduce_stats(const float2* __restrict__ part,
                                                    float2* __restrict__ stats) {
    const int rid = blockIdx.x * 256 + threadIdx.x;   // [0, NB*S)
    const int b = rid >> 11, row = rid & (S - 1);
    float2 p[16];
    float M = -3.4e38f;
#pragma unroll
    for (int kt = 0; kt < 16; kt++) {
        p[kt] = part[((size_t)(b * 16 + kt)) * S + row];
        M = fmaxf(M, p[kt].x);
    }
    float L = 0.f;
#pragma unroll
    for (int kt = 0; kt < 16; kt++) L += p[kt].y * __expf(p[kt].x - M);
    stats[rid] = make_float2(M, 1.0f / L);
}

__global__ __launch_bounds__(256, 2) void qk_kernel(const float* __restrict__ Q,
                                                    const float* __restrict__ Km,
                                                    float* __restrict__ Sc,
                                                    const void* __restrict__ maskp,
                                                    const int* __restrict__ flagp,
                                                    float2* __restrict__ part,
                                                    const int fuse) {
    const int kt = blockIdx.x, qt = blockIdx.y, b = blockIdx.z;
    const float* Qb = Q + ((size_t)b * S + qt * 128) * Dh;
    const float* Kb = Km + ((size_t)b * S + kt * 128) * Dh;
    __shared__ short As[128][72];
    __shared__ short Bs[128][72];
    __shared__ __align__(16) unsigned char Ms[128][144];
    const int t = threadIdx.x;
    const int w = t >> 6, lane = t & 63, fr = lane & 15, quad = lane >> 4;
    const int mw = (w >> 1) * 64, nw = (w & 1) * 64;
    f32x4 acc[4][4] = {};

    if (fuse) {
        const int flag = *flagp;
        if (flag) {
            const unsigned char* Mb = (const unsigned char*)maskp + ((size_t)b * S + qt * 128) * S + (size_t)kt * 128;
#pragma unroll
            for (int i = 0; i < 4; i++) {
                int idx = t + i * 256;
                int r = idx >> 3, c = (idx & 7) * 16;
                *(int4*)&Ms[r][c] = *(const int4*)(Mb + (size_t)r * S + c);
            }
        } else {
            const int* Mb = (const int*)maskp + ((size_t)b * S + qt * 128) * S + (size_t)kt * 128;
#pragma unroll
            for (int i = 0; i < 16; i++) {
                int idx = t + i * 256;
                int r = idx >> 5, c = (idx & 31) * 4;
                int4 mv = *(const int4*)(Mb + (size_t)r * S + c);
                uchar4 o;
                o.x = (unsigned char)(mv.x != 0);
                o.y = (unsigned char)(mv.y != 0);
                o.z = (unsigned char)(mv.z != 0);
                o.w = (unsigned char)(mv.w != 0);
                *(uchar4*)&Ms[r][c] = o;
            }
        }
    }

    for (int k0 = 0; k0 < Dh; k0 += 64) {
        __syncthreads();
#pragma unroll
        for (int i = 0; i < 8; i++) {
            int idx = t + i * 256;
            int r = idx >> 4, c = (idx & 15) << 2;
            float4 qv = *(const float4*)(Qb + r * Dh + k0 + c);
            float4 kv = *(const float4*)(Kb + r * Dh + k0 + c);
            *(s16x4*)&As[r][c] = pack4(qv);
            *(s16x4*)&Bs[r][c] = pack4(kv);
        }
        __syncthreads();
#pragma unroll
        for (int kc = 0; kc < 2; kc++) {
            const int ko = kc * 32 + quad * 8;
            bf16x8 af[4], bf[4];
#pragma unroll
            for (int mi = 0; mi < 4; mi++) af[mi] = *(const bf16x8*)&As[mw + mi * 16 + fr][ko];
#pragma unroll
            for (int ni = 0; ni < 4; ni++) bf[ni] = *(const bf16x8*)&Bs[nw + ni * 16 + fr][ko];
#pragma unroll
            for (int mi = 0; mi < 4; mi++)
#pragma unroll
                for (int ni = 0; ni < 4; ni++)
                    acc[mi][ni] = __builtin_amdgcn_mfma_f32_16x16x32_bf16(af[mi], bf[ni], acc[mi][ni], 0, 0, 0);
        }
    }

    __syncthreads();
    float2* pm = (float2*)&As[0][0];
    float* ScB = Sc + (size_t)b * S * S;
#pragma unroll
    for (int mi = 0; mi < 4; mi++)
#pragma unroll
        for (int r = 0; r < 4; r++) {
            const int lrow = mw + mi * 16 + quad * 4 + r;
            const size_t grow = (size_t)(qt * 128 + lrow);
            float s[4];
#pragma unroll
            for (int ni = 0; ni < 4; ni++) {
                const int lcol = nw + ni * 16 + fr;
                float v = acc[mi][ni][r] * SCALE;
                if (fuse && Ms[lrow][lcol]) v = NEG_BIG;
                s[ni] = v;
                ScB[grow * S + kt * 128 + lcol] = v;
            }
            if (fuse) {
                float mx = fmaxf(fmaxf(s[0], s[1]), fmaxf(s[2], s[3]));
#pragma unroll
                for (int o = 8; o > 0; o >>= 1) mx = fmaxf(mx, __shfl_xor(mx, o, 64));
                float lsum = __expf(s[0] - mx) + __expf(s[1] - mx) +
                             __expf(s[2] - mx) + __expf(s[3] - mx);
#pragma unroll
                for (int o = 8; o > 0; o >>= 1) lsum += __shfl_xor(lsum, o, 64);
                if (fr == 0) pm[lrow * 2 + (w & 1)] = make_float2(mx, lsum);
            }
        }

    if (fuse) {
        __syncthreads();
        if (t < 128) {
            float2 a = pm[t * 2 + 0], c = pm[t * 2 + 1];
            float M = fmaxf(a.x, c.x);
            float L = a.y * __expf(a.x - M) + c.y * __expf(c.x - M);
            part[((size_t)(b * 16 + kt)) * S + qt * 128 + t] = make_float2(M, L);
        }
    }
}

__global__ __launch_bounds__(256) void softmax_kernel(float* __restrict__ Sc,
                                                      const void* __restrict__ maskp,
                                                      const int* __restrict__ flagp) {
    const int b = blockIdx.y;
    const int w = threadIdx.x >> 6, lane = threadIdx.x & 63;
    const int row = blockIdx.x * 4 + w;
    float* R = Sc + ((size_t)b * S + row) * S;
    float4* R4 = (float4*)R;
    const int flag = flagp ? *flagp : 0;

    float sv[32];
    if (flag) {
        const uchar4* M4 = (const uchar4*)((const unsigned char*)maskp + ((size_t)b * S + row) * S);
#pragma unroll
        for (int j = 0; j < 8; j++) {
            float4 v = R4[lane + 64 * j];
            uchar4 mv = M4[lane + 64 * j];
            sv[4 * j + 0] = mv.x ? NEG_BIG : v.x;
            sv[4 * j + 1] = mv.y ? NEG_BIG : v.y;
            sv[4 * j + 2] = mv.z ? NEG_BIG : v.z;
            sv[4 * j + 3] = mv.w ? NEG_BIG : v.w;
        }
    } else {
        const int4* M4 = (const int4*)((const int*)maskp + ((size_t)b * S + row) * S);
#pragma unroll
        for (int j = 0; j < 8; j++) {
            float4 v = R4[lane + 64 * j];
            int4 mv = M4[lane + 64 * j];
            sv[4 * j + 0] = mv.x ? NEG_BIG : v.x;
            sv[4 * j + 1] = mv.y ? NEG_BIG : v.y;
            sv[4 * j + 2] = mv.z ? NEG_BIG : v.z;
            sv[4 * j + 3] = mv.w ? NEG_BIG : v.w;
        }
    }

    float mx = sv[0];
#pragma unroll
    for (int i = 1; i < 32; i++) mx = fmaxf(mx, sv[i]);
    for (int o = 32; o > 0; o >>= 1) mx = fmaxf(mx, __shfl_xor(mx, o, 64));

    float sum = 0.f;
#pragma unroll
    for (int i = 0; i < 32; i++) {
        sv[i] = __expf(sv[i] - mx);
        sum += sv[i];
    }
    for (int o = 32; o > 0; o >>= 1) sum += __shfl_xor(sum, o, 64);
    const float inv = 1.0f / sum;

#pragma unroll
    for (int j = 0; j < 8; j++) {
        float4 p;
        p.x = sv[4 * j + 0] * inv;
        p.y = sv[4 * j + 1] * inv;
        p.z = sv[4 * j + 2] * inv;
        p.w = sv[4 * j + 3] * inv;
        R4[lane + 64 * j] = p;
    }
}

__global__ __launch_bounds__(256, 2) void pv_kernel(float* __restrict__ Sc,
                                                    const float* __restrict__ V,
                                                    const short* __restrict__ Vt,
                                                    const int useVt,
                                                    float* __restrict__ Out,
                                                    const float2* __restrict__ stats,
                                                    const int fuse) {
    const int mt = blockIdx.x, b = blockIdx.y;
    float* ScB = Sc + (size_t)b * S * S + (size_t)mt * 64 * S;
    const float* Vb = V + (size_t)b * S * Dh;
    const short* VtB = Vt + (size_t)b * Dh * S;
    float* OutB = Out + ((size_t)b * S + mt * 64) * Dh;
    __shared__ short As[64][72];
    __shared__ float2 sstat[64];
    const int t = threadIdx.x, w = t >> 6, lane = t & 63, fr = lane & 15, quad = lane >> 4;
    const int mw = (w >> 1) * 32, nw = (w & 1) * 64;
    f32x4 acc[2][4] = {};

    if (fuse && t < 64) sstat[t] = stats[(size_t)b * S + mt * 64 + t];

    for (int k0 = 0; k0 < S; k0 += 64) {
        __syncthreads();
#pragma unroll
        for (int i = 0; i < 4; i++) {
            int idx = t + i * 256;
            int r = idx >> 4, c = (idx & 15) << 2;
            float4 v = *(const float4*)(ScB + (size_t)r * S + k0 + c);
            if (fuse) {
                float2 stv = sstat[r];
                v.x = __expf(v.x - stv.x) * stv.y;
                v.y = __expf(v.y - stv.x) * stv.y;
                v.z = __expf(v.z - stv.x) * stv.y;
                v.w = __expf(v.w - stv.x) * stv.y;
                *(float4*)(ScB + (size_t)r * S + k0 + c) = v;
            }
            *(s16x4*)&As[r][c] = pack4(v);
        }
        __syncthreads();
#pragma unroll
        for (int kc = 0; kc < 2; kc++) {
            const int ko = kc * 32 + quad * 8;
            bf16x8 af[2], bf[4];
#pragma unroll
            for (int mi = 0; mi < 2; mi++) af[mi] = *(const bf16x8*)&As[mw + mi * 16 + fr][ko];
            if (useVt) {
#pragma unroll
                for (int ni = 0; ni < 4; ni++)
                    bf[ni] = *(const bf16x8*)(VtB + (size_t)(nw + ni * 16 + fr) * S + k0 + ko);
            } else {
#pragma unroll
                for (int ni = 0; ni < 4; ni++) {
                    int n = nw + ni * 16 + fr;
#pragma unroll
                    for (int j = 0; j < 8; j++) bf[ni][j] = f2bf(Vb[(size_t)(k0 + ko + j) * Dh + n]);
                }
            }
#pragma unroll
            for (int mi = 0; mi < 2; mi++)
#pragma unroll
                for (int ni = 0; ni < 4; ni++)
                    acc[mi][ni] = __builtin_amdgcn_mfma_f32_16x16x32_bf16(af[mi], bf[ni], acc[mi][ni], 0, 0, 0);
        }
    }

#pragma unroll
    for (int mi = 0; mi < 2; mi++)
#pragma unroll
        for (int ni = 0; ni < 4; ni++)
#pragma unroll
            for (int r = 0; r < 4; r++) {
                int row = mw + mi * 16 + quad * 4 + r;
                int col = nw + ni * 16 + fr;
                OutB[(size_t)row * Dh + col] = acc[mi][ni][r];
            }
}

extern "C" void kernel_launch(void* const* d_in, const int* in_sizes, int n_in,
                              void* d_out, int out_size, void* d_ws, size_t ws_size,
                              hipStream_t stream) {
    const float* Q = (const float*)d_in[0];
    const float* Km = (const float*)d_in[1];
    const float* V = (const float*)d_in[2];
    const void* M = d_in[3];
    float* out = (float*)d_out;
    float* attn = out + OUT_ELEMS;

    const size_t VT_BYTES   = (size_t)NB * Dh * S * sizeof(short);   // 8 MB
    const size_t QBF_BYTES  = (size_t)NB * S * Dh * sizeof(short);   // 8 MB
    const size_t KBF_BYTES  = QBF_BYTES;                             // 8 MB
    const size_t STATS_BYTES = (size_t)NB * S * sizeof(float2);      // 256 KB
    const size_t REQ_NEW = VT_BYTES + QBF_BYTES + KBF_BYTES + STATS_BYTES + 64;

    if (ws_size >= REQ_NEW) {
        short* Vt   = (short*)d_ws;
        short* Qbf  = (short*)((char*)d_ws + VT_BYTES);
        short* Kbf  = (short*)((char*)d_ws + VT_BYTES + QBF_BYTES);
        float2* stats = (float2*)((char*)d_ws + VT_BYTES + QBF_BYTES + KBF_BYTES);
        int* flag = (int*)((char*)d_ws + VT_BYTES + QBF_BYTES + KBF_BYTES + STATS_BYTES);

        detect_mask<<<1, 256, 0, stream>>>((const unsigned char*)M, flag);
        transpose_v<<<dim3(32, NB), 256, 0, stream>>>(V, Vt);
        cvt_bf16<<<2048, 256, 0, stream>>>(Q, Qbf);
        cvt_bf16<<<2048, 256, 0, stream>>>(Km, Kbf);
        flash_pv<<<512, 256, 0, stream>>>(Qbf, Kbf, Vt, M, flag, stats, out);
        attn_write<<<4096, 256, 0, stream>>>(Qbf, Kbf, M, flag, stats, attn);
        return;
    }

    // ---------------- fallback: verified round-2 path ----------------
    float2* part = (float2*)d_out;   // 4 MB partials in the out region
    int useVt = 0, fuse = 0;
    short* Vt = nullptr;
    float2* stats = nullptr;
    int* flag = nullptr;

    if (ws_size >= VT_BYTES + STATS_BYTES + 64) {
        useVt = 1; fuse = 1;
        Vt = (short*)d_ws;
        stats = (float2*)((char*)d_ws + VT_BYTES);
        flag = (int*)((char*)d_ws + VT_BYTES + STATS_BYTES);
    } else if (ws_size >= VT_BYTES + 64) {
        useVt = 1;
        Vt = (short*)d_ws;
        flag = (int*)((char*)d_ws + VT_BYTES);
    } else if (ws_size >= 64) {
        flag = (int*)d_ws;
    }

    if (flag) detect_mask<<<1, 256, 0, stream>>>((const unsigned char*)M, flag);
    if (useVt) transpose_v<<<dim3(32, NB), 256, 0, stream>>>(V, Vt);

    qk_kernel<<<dim3(16, 16, NB), 256, 0, stream>>>(Q, Km, attn, M, flag, part, fuse);

    if (fuse) {
        reduce_stats<<<dim3((NB * S) / 256), 256, 0, stream>>>(part, stats);
        pv_kernel<<<dim3(32, NB), 256, 0, stream>>>(attn, V, Vt, useVt, out, stats, 1);
    } else {
        softmax_kernel<<<dim3(512, NB), 256, 0, stream>>>(attn, M, flag);
        pv_kernel<<<dim3(32, NB), 256, 0, stream>>>(attn, V, Vt, useVt, out, nullptr, 0);
    }
}